// Round 1
// baseline (808.529 us; speedup 1.0000x reference)
//
#include <hip/hip_runtime.h>

#define TILE 128
#define BK 32
#define LDSS 132  // padded LDS row stride (words), keeps float4 alignment, breaks conflicts

// -------- shared 8x8 micro-kernel: acc += A_tile^T-slice * B_tile-slice --------
__device__ __forceinline__ void micro_mm(const float* As, const float* Bs,
                                         int tr, int tc, float acc[8][8]) {
#pragma unroll
  for (int kk = 0; kk < BK; ++kk) {
    float4 a0 = *reinterpret_cast<const float4*>(&As[kk * LDSS + tr * 4]);
    float4 a1 = *reinterpret_cast<const float4*>(&As[kk * LDSS + 64 + tr * 4]);
    float4 b0 = *reinterpret_cast<const float4*>(&Bs[kk * LDSS + tc * 4]);
    float4 b1 = *reinterpret_cast<const float4*>(&Bs[kk * LDSS + 64 + tc * 4]);
    float a[8] = {a0.x, a0.y, a0.z, a0.w, a1.x, a1.y, a1.z, a1.w};
    float b[8] = {b0.x, b0.y, b0.z, b0.w, b1.x, b1.y, b1.z, b1.w};
#pragma unroll
    for (int i = 0; i < 8; ++i)
#pragma unroll
      for (int j = 0; j < 8; ++j)
        acc[i][j] = fmaf(a[i], b[j], acc[i][j]);
  }
}

__device__ __forceinline__ int row_of(int tr, int i) {
  return (i < 4) ? (tr * 4 + i) : (64 + tr * 4 + (i - 4));
}

// -------- K1: qk[32768,128] = xf[32768,1024] @ [Qm | Km][1024,128] --------
__global__ __launch_bounds__(256) void k1_qk(const float* __restrict__ x,
                                             const float* __restrict__ Qm,
                                             const float* __restrict__ Km,
                                             float* __restrict__ qk) {
  __shared__ float As[BK * LDSS];
  __shared__ float Bs[BK * LDSS];
  int t = threadIdx.x;
  int tc = t & 15, tr = t >> 4;
  int rowBase = blockIdx.x * TILE;
  float acc[8][8] = {};

  for (int k0 = 0; k0 < 1024; k0 += BK) {
    // A tile: xf rows [rowBase..+128), cols [k0..k0+32) -> transpose to As[k][row]
#pragma unroll
    for (int r = 0; r < 4; ++r) {
      int row = (t >> 3) + 32 * r;
      int col = (t & 7) * 4;
      float4 v = *reinterpret_cast<const float4*>(&x[(long)(rowBase + row) * 1024 + k0 + col]);
      As[(col + 0) * LDSS + row] = v.x;
      As[(col + 1) * LDSS + row] = v.y;
      As[(col + 2) * LDSS + row] = v.z;
      As[(col + 3) * LDSS + row] = v.w;
    }
    // B tile: rows k, 128 cols = [Qm | Km], direct k-major
#pragma unroll
    for (int r = 0; r < 4; ++r) {
      int kk = (t >> 5) + 8 * r;
      int col = (t & 31) * 4;
      const float* src = (col < 64) ? &Qm[(long)(k0 + kk) * 64 + col]
                                    : &Km[(long)(k0 + kk) * 64 + (col - 64)];
      *reinterpret_cast<float4*>(&Bs[kk * LDSS + col]) =
          *reinterpret_cast<const float4*>(src);
    }
    __syncthreads();
    micro_mm(As, Bs, tr, tc, acc);
    __syncthreads();
  }
#pragma unroll
  for (int i = 0; i < 8; ++i) {
    int row = rowBase + row_of(tr, i);
    float4 v0 = make_float4(acc[i][0], acc[i][1], acc[i][2], acc[i][3]);
    float4 v1 = make_float4(acc[i][4], acc[i][5], acc[i][6], acc[i][7]);
    *reinterpret_cast<float4*>(&qk[(long)row * 128 + tc * 4]) = v0;
    *reinterpret_cast<float4*>(&qk[(long)row * 128 + 64 + tc * 4]) = v1;
  }
}

// -------- K2a: s[b,i,j] = exp(sigmoid(q[b,i,:] . k[b,j,:])) --------
__global__ __launch_bounds__(256) void k2a_energy(const float* __restrict__ qk,
                                                  float* __restrict__ s) {
  __shared__ float As[BK * LDSS];
  __shared__ float Bs[BK * LDSS];
  int t = threadIdx.x;
  int tc = t & 15, tr = t >> 4;
  int b = blockIdx.x >> 4;
  int iBase = ((blockIdx.x >> 2) & 3) * TILE;
  int jBase = (blockIdx.x & 3) * TILE;
  const float* qb = qk + (long)b * 512 * 128;
  float acc[8][8] = {};

  for (int d0 = 0; d0 < 64; d0 += BK) {
#pragma unroll
    for (int r = 0; r < 4; ++r) {
      int i = (t >> 3) + 32 * r;
      int d = (t & 7) * 4;
      float4 va = *reinterpret_cast<const float4*>(&qb[(long)(iBase + i) * 128 + d0 + d]);
      As[(d + 0) * LDSS + i] = va.x;
      As[(d + 1) * LDSS + i] = va.y;
      As[(d + 2) * LDSS + i] = va.z;
      As[(d + 3) * LDSS + i] = va.w;
      float4 vk = *reinterpret_cast<const float4*>(&qb[(long)(jBase + i) * 128 + 64 + d0 + d]);
      Bs[(d + 0) * LDSS + i] = vk.x;
      Bs[(d + 1) * LDSS + i] = vk.y;
      Bs[(d + 2) * LDSS + i] = vk.z;
      Bs[(d + 3) * LDSS + i] = vk.w;
    }
    __syncthreads();
    micro_mm(As, Bs, tr, tc, acc);
    __syncthreads();
  }
  float* sb = s + (long)b * 512 * 512;
#pragma unroll
  for (int i = 0; i < 8; ++i) {
    int row = iBase + row_of(tr, i);
    float v[8];
#pragma unroll
    for (int j = 0; j < 8; ++j) {
      float sg = 1.0f / (1.0f + __expf(-acc[i][j]));
      v[j] = __expf(sg);
    }
    *reinterpret_cast<float4*>(&sb[(long)row * 512 + jBase + tc * 4]) =
        make_float4(v[0], v[1], v[2], v[3]);
    *reinterpret_cast<float4*>(&sb[(long)row * 512 + jBase + 64 + tc * 4]) =
        make_float4(v[4], v[5], v[6], v[7]);
  }
}

// -------- K2b: column softmax normalize (axis=-2) in place; attbias = att^T . bias --------
__global__ __launch_bounds__(256) void k2b_softmax(float* __restrict__ s,
                                                   const float* __restrict__ bias,
                                                   float* __restrict__ attbias) {
  int b = blockIdx.x >> 3;
  int jBase = (blockIdx.x & 7) * 64;
  int tx = threadIdx.x & 63;
  int ty = threadIdx.x >> 6;
  float* sb = s + (long)b * 512 * 512 + jBase;
  float sum = 0.f, sumb = 0.f;
  for (int i = ty; i < 512; i += 4) {
    float v = sb[(long)i * 512 + tx];
    sum += v;
    sumb += v * bias[i];
  }
  __shared__ float red[4][64];
  __shared__ float redb[4][64];
  red[ty][tx] = sum;
  redb[ty][tx] = sumb;
  __syncthreads();
  if (ty == 0) {
    float tot = red[0][tx] + red[1][tx] + red[2][tx] + red[3][tx];
    float totb = redb[0][tx] + redb[1][tx] + redb[2][tx] + redb[3][tx];
    float r = 1.0f / tot;
    red[0][tx] = r;
    attbias[(long)b * 512 + jBase + tx] = totb * r;
  }
  __syncthreads();
  float r = red[0][tx];
  for (int i = ty; i < 512; i += 4) {
    sb[(long)i * 512 + tx] *= r;
  }
}

// -------- K3: weff[b,j,c] = sum_i att[b,i,j] * vw[i,c]  (A^T GEMM, K=i) --------
__global__ __launch_bounds__(256) void k3_weff(const float* __restrict__ att,
                                               const float* __restrict__ vw,
                                               float* __restrict__ weff) {
  __shared__ float As[BK * LDSS];  // [i][j] : already K-major
  __shared__ float Bs[BK * LDSS];  // [i][c] : already K-major
  int t = threadIdx.x;
  int tc = t & 15, tr = t >> 4;
  int b = blockIdx.x >> 4;
  int jBase = ((blockIdx.x >> 2) & 3) * TILE;
  int cBase = (blockIdx.x & 3) * TILE;
  const float* ab = att + (long)b * 262144;
  float acc[8][8] = {};

  for (int k0 = 0; k0 < 512; k0 += BK) {
#pragma unroll
    for (int r = 0; r < 4; ++r) {
      int i = (t >> 5) + 8 * r;
      int j = (t & 31) * 4;
      *reinterpret_cast<float4*>(&As[i * LDSS + j]) =
          *reinterpret_cast<const float4*>(&ab[(long)(k0 + i) * 512 + jBase + j]);
      *reinterpret_cast<float4*>(&Bs[i * LDSS + j]) =
          *reinterpret_cast<const float4*>(&vw[(long)(k0 + i) * 512 + cBase + j]);
    }
    __syncthreads();
    micro_mm(As, Bs, tr, tc, acc);
    __syncthreads();
  }
  float* wb = weff + (long)b * 262144;
#pragma unroll
  for (int i = 0; i < 8; ++i) {
    int row = jBase + row_of(tr, i);
    *reinterpret_cast<float4*>(&wb[(long)row * 512 + cBase + tc * 4]) =
        make_float4(acc[i][0], acc[i][1], acc[i][2], acc[i][3]);
    *reinterpret_cast<float4*>(&wb[(long)row * 512 + cBase + 64 + tc * 4]) =
        make_float4(acc[i][4], acc[i][5], acc[i][6], acc[i][7]);
  }
}

// -------- K4: out[b,j,n] = sum_c weff[b,j,c] * xf[b,c,n] + attbias[b,j] --------
__global__ __launch_bounds__(256) void k4_out(const float* __restrict__ weff,
                                              const float* __restrict__ x,
                                              const float* __restrict__ attbias,
                                              float* __restrict__ out) {
  __shared__ float As[BK * LDSS];  // [c][j] transposed
  __shared__ float Bs[BK * LDSS];  // [c][n] direct
  int t = threadIdx.x;
  int tc = t & 15, tr = t >> 4;
  int b = blockIdx.x >> 5;
  int jBase = ((blockIdx.x >> 3) & 3) * TILE;
  int nBase = (blockIdx.x & 7) * TILE;
  const float* wb = weff + (long)b * 262144;
  const float* xb = x + (long)b * 524288;
  float acc[8][8] = {};

  for (int c0 = 0; c0 < 512; c0 += BK) {
#pragma unroll
    for (int r = 0; r < 4; ++r) {
      int j = (t >> 3) + 32 * r;
      int c = (t & 7) * 4;
      float4 v = *reinterpret_cast<const float4*>(&wb[(long)(jBase + j) * 512 + c0 + c]);
      As[(c + 0) * LDSS + j] = v.x;
      As[(c + 1) * LDSS + j] = v.y;
      As[(c + 2) * LDSS + j] = v.z;
      As[(c + 3) * LDSS + j] = v.w;
    }
#pragma unroll
    for (int r = 0; r < 4; ++r) {
      int c = (t >> 5) + 8 * r;
      int n = (t & 31) * 4;
      *reinterpret_cast<float4*>(&Bs[c * LDSS + n]) =
          *reinterpret_cast<const float4*>(&xb[(long)(c0 + c) * 1024 + nBase + n]);
    }
    __syncthreads();
    micro_mm(As, Bs, tr, tc, acc);
    __syncthreads();
  }
#pragma unroll
  for (int i = 0; i < 8; ++i) {
    int row = jBase + row_of(tr, i);
    float ab = attbias[(long)b * 512 + row];
    float4 v0 = make_float4(acc[i][0] + ab, acc[i][1] + ab, acc[i][2] + ab, acc[i][3] + ab);
    float4 v1 = make_float4(acc[i][4] + ab, acc[i][5] + ab, acc[i][6] + ab, acc[i][7] + ab);
    *reinterpret_cast<float4*>(&out[(long)b * 524288 + (long)row * 1024 + nBase + tc * 4]) = v0;
    *reinterpret_cast<float4*>(&out[(long)b * 524288 + (long)row * 1024 + nBase + 64 + tc * 4]) = v1;
  }
}

extern "C" void kernel_launch(void* const* d_in, const int* in_sizes, int n_in,
                              void* d_out, int out_size, void* d_ws, size_t ws_size,
                              hipStream_t stream) {
  const float* x  = (const float*)d_in[0];
  const float* Qm = (const float*)d_in[1];
  const float* Km = (const float*)d_in[2];
  const float* vw = (const float*)d_in[3];
  const float* vb = (const float*)d_in[4];
  float* out = (float*)d_out;

  float* ws = (float*)d_ws;
  float* qk      = ws;                                   // 32768*128   = 4,194,304 f
  float* s       = ws + 4194304;                         // 64*512*512  = 16,777,216 f
  float* weff    = ws + 4194304 + 16777216;              // 16,777,216 f
  float* attbias = ws + 4194304 + 16777216 + 16777216;   // 32,768 f
  // total ws use: 37,781,504 floats = 151.1 MB

  k1_qk<<<256, 256, 0, stream>>>(x, Qm, Km, qk);
  k2a_energy<<<1024, 256, 0, stream>>>(qk, s);
  k2b_softmax<<<512, 256, 0, stream>>>(s, vb, attbias);
  k3_weff<<<1024, 256, 0, stream>>>(s, vw, weff);
  k4_out<<<2048, 256, 0, stream>>>(weff, x, attbias, out);
}

// Round 2
// 329.990 us; speedup vs baseline: 2.4502x; 2.4502x over previous
//
#include <hip/hip_runtime.h>

#define TILE 128
#define BK 32
#define LDSS 132

typedef __attribute__((ext_vector_type(8))) short bf16x8;
typedef __attribute__((ext_vector_type(4))) float f32x4;

__device__ __forceinline__ unsigned short f2bf(float f) {
  unsigned u = __builtin_bit_cast(unsigned, f);
  unsigned r = (u + 0x7FFFu + ((u >> 16) & 1u)) >> 16;
  return (unsigned short)r;
}
__device__ __forceinline__ float bf2f(unsigned short h) {
  return __builtin_bit_cast(float, (unsigned)h << 16);
}

__device__ __forceinline__ void gld_lds16(const void* g, void* l) {
  __builtin_amdgcn_global_load_lds(
      (const __attribute__((address_space(1))) unsigned int*)g,
      (__attribute__((address_space(3))) unsigned int*)l, 16, 0, 0);
}

// -------- fp32 8x8 micro-kernel (K1, K2a) --------
__device__ __forceinline__ void micro_mm(const float* As, const float* Bs,
                                         int tr, int tc, float acc[8][8]) {
#pragma unroll
  for (int kk = 0; kk < BK; ++kk) {
    float4 a0 = *reinterpret_cast<const float4*>(&As[kk * LDSS + tr * 4]);
    float4 a1 = *reinterpret_cast<const float4*>(&As[kk * LDSS + 64 + tr * 4]);
    float4 b0 = *reinterpret_cast<const float4*>(&Bs[kk * LDSS + tc * 4]);
    float4 b1 = *reinterpret_cast<const float4*>(&Bs[kk * LDSS + 64 + tc * 4]);
    float a[8] = {a0.x, a0.y, a0.z, a0.w, a1.x, a1.y, a1.z, a1.w};
    float b[8] = {b0.x, b0.y, b0.z, b0.w, b1.x, b1.y, b1.z, b1.w};
#pragma unroll
    for (int i = 0; i < 8; ++i)
#pragma unroll
      for (int j = 0; j < 8; ++j)
        acc[i][j] = fmaf(a[i], b[j], acc[i][j]);
  }
}

__device__ __forceinline__ int row_of(int tr, int i) {
  return (i < 4) ? (tr * 4 + i) : (64 + tr * 4 + (i - 4));
}

// -------- K1: qk[32768,128] = xf[32768,1024] @ [Qm | Km][1024,128] (fp32) --------
__global__ __launch_bounds__(256) void k1_qk(const float* __restrict__ x,
                                             const float* __restrict__ Qm,
                                             const float* __restrict__ Km,
                                             float* __restrict__ qk) {
  __shared__ float As[BK * LDSS];
  __shared__ float Bs[BK * LDSS];
  int t = threadIdx.x;
  int tc = t & 15, tr = t >> 4;
  int rowBase = blockIdx.x * TILE;
  float acc[8][8] = {};

  for (int k0 = 0; k0 < 1024; k0 += BK) {
#pragma unroll
    for (int r = 0; r < 4; ++r) {
      int row = (t >> 3) + 32 * r;
      int col = (t & 7) * 4;
      float4 v = *reinterpret_cast<const float4*>(&x[(long)(rowBase + row) * 1024 + k0 + col]);
      As[(col + 0) * LDSS + row] = v.x;
      As[(col + 1) * LDSS + row] = v.y;
      As[(col + 2) * LDSS + row] = v.z;
      As[(col + 3) * LDSS + row] = v.w;
    }
#pragma unroll
    for (int r = 0; r < 4; ++r) {
      int kk = (t >> 5) + 8 * r;
      int col = (t & 31) * 4;
      const float* src = (col < 64) ? &Qm[(long)(k0 + kk) * 64 + col]
                                    : &Km[(long)(k0 + kk) * 64 + (col - 64)];
      *reinterpret_cast<float4*>(&Bs[kk * LDSS + col]) =
          *reinterpret_cast<const float4*>(src);
    }
    __syncthreads();
    micro_mm(As, Bs, tr, tc, acc);
    __syncthreads();
  }
#pragma unroll
  for (int i = 0; i < 8; ++i) {
    int row = rowBase + row_of(tr, i);
    *reinterpret_cast<float4*>(&qk[(long)row * 128 + tc * 4]) =
        make_float4(acc[i][0], acc[i][1], acc[i][2], acc[i][3]);
    *reinterpret_cast<float4*>(&qk[(long)row * 128 + 64 + tc * 4]) =
        make_float4(acc[i][4], acc[i][5], acc[i][6], acc[i][7]);
  }
}

// -------- K2a: st[b,j,i] = exp(sigmoid(k_j . q_i))  (fp32 compute, bf16 out) --------
__global__ __launch_bounds__(256) void k2a_energy(const float* __restrict__ qk,
                                                  unsigned short* __restrict__ st) {
  __shared__ float As[BK * LDSS];
  __shared__ float Bs[BK * LDSS];
  int t = threadIdx.x;
  int tc = t & 15, tr = t >> 4;
  int b = blockIdx.x >> 4;
  int jBase = ((blockIdx.x >> 2) & 3) * TILE;   // output rows j (from k-vectors)
  int iBase = (blockIdx.x & 3) * TILE;          // output cols i (from q-vectors)
  const float* qb = qk + (long)b * 512 * 128;
  float acc[8][8] = {};

  for (int d0 = 0; d0 < 64; d0 += BK) {
#pragma unroll
    for (int r = 0; r < 4; ++r) {
      int rl = (t >> 3) + 32 * r;
      int d = (t & 7) * 4;
      // A tile: k-half rows jBase
      float4 va = *reinterpret_cast<const float4*>(&qb[(long)(jBase + rl) * 128 + 64 + d0 + d]);
      As[(d + 0) * LDSS + rl] = va.x;
      As[(d + 1) * LDSS + rl] = va.y;
      As[(d + 2) * LDSS + rl] = va.z;
      As[(d + 3) * LDSS + rl] = va.w;
      // B tile: q-half rows iBase
      float4 vk = *reinterpret_cast<const float4*>(&qb[(long)(iBase + rl) * 128 + d0 + d]);
      Bs[(d + 0) * LDSS + rl] = vk.x;
      Bs[(d + 1) * LDSS + rl] = vk.y;
      Bs[(d + 2) * LDSS + rl] = vk.z;
      Bs[(d + 3) * LDSS + rl] = vk.w;
    }
    __syncthreads();
    micro_mm(As, Bs, tr, tc, acc);
    __syncthreads();
  }
  unsigned short* sb = st + (long)b * 512 * 512;
#pragma unroll
  for (int i = 0; i < 8; ++i) {
    int row = jBase + row_of(tr, i);
    unsigned short v[8];
#pragma unroll
    for (int j = 0; j < 8; ++j) {
      float sg = 1.0f / (1.0f + __expf(-acc[i][j]));
      v[j] = f2bf(__expf(sg));
    }
    *reinterpret_cast<uint2*>(&sb[(long)row * 512 + iBase + tc * 4]) =
        *reinterpret_cast<uint2*>(&v[0]);
    *reinterpret_cast<uint2*>(&sb[(long)row * 512 + iBase + 64 + tc * 4]) =
        *reinterpret_cast<uint2*>(&v[4]);
  }
}

// -------- K2b: per-row (j) sums of st -> rsum = 1/sum, attbias = (st.bias)/sum --------
__global__ __launch_bounds__(256) void k2b_rsum(const unsigned short* __restrict__ st,
                                                const float* __restrict__ bias,
                                                float* __restrict__ rsum,
                                                float* __restrict__ attbias) {
  int jg = blockIdx.x * 4 + (threadIdx.x >> 6);  // global row 0..32767
  int l = threadIdx.x & 63;
  const unsigned short* row = st + (long)jg * 512 + l * 8;
  ushort4 u0 = *reinterpret_cast<const ushort4*>(row);
  ushort4 u1 = *reinterpret_cast<const ushort4*>(row + 4);
  float4 b0 = *reinterpret_cast<const float4*>(&bias[l * 8]);
  float4 b1 = *reinterpret_cast<const float4*>(&bias[l * 8 + 4]);
  float f0 = bf2f(u0.x), f1 = bf2f(u0.y), f2 = bf2f(u0.z), f3 = bf2f(u0.w);
  float f4 = bf2f(u1.x), f5 = bf2f(u1.y), f6 = bf2f(u1.z), f7 = bf2f(u1.w);
  float sum = (f0 + f1) + (f2 + f3) + ((f4 + f5) + (f6 + f7));
  float sumb = f0 * b0.x + f1 * b0.y + f2 * b0.z + f3 * b0.w +
               f4 * b1.x + f5 * b1.y + f6 * b1.z + f7 * b1.w;
#pragma unroll
  for (int off = 32; off > 0; off >>= 1) {
    sum += __shfl_down(sum, off);
    sumb += __shfl_down(sumb, off);
  }
  if (l == 0) {
    float r = 1.0f / sum;
    rsum[jg] = r;
    attbias[jg] = sumb * r;
  }
}

// -------- transpose + fp32->bf16 convert: out[c][r] = bf16(in[r][c]), 64x64 tiles ----
__global__ __launch_bounds__(256) void transpose_conv(const float* __restrict__ in,
                                                      unsigned short* __restrict__ out,
                                                      int inRows, int inCols,
                                                      long inBatch, long outBatch) {
  __shared__ unsigned short lt[64][65];
  int b = blockIdx.z;
  int r0 = blockIdx.y * 64;
  int c0 = blockIdx.x * 64;
  const float* I = in + (long)b * inBatch;
  unsigned short* O = out + (long)b * outBatch;
  int t = threadIdx.x;
  int cl = (t & 15) * 4;
  int rl = t >> 4;
#pragma unroll
  for (int rr = 0; rr < 4; ++rr) {
    int r = rl + rr * 16;
    float4 v = *reinterpret_cast<const float4*>(&I[(long)(r0 + r) * inCols + c0 + cl]);
    lt[cl + 0][r] = f2bf(v.x);
    lt[cl + 1][r] = f2bf(v.y);
    lt[cl + 2][r] = f2bf(v.z);
    lt[cl + 3][r] = f2bf(v.w);
  }
  __syncthreads();
#pragma unroll
  for (int rr = 0; rr < 4; ++rr) {
    int c = rl + rr * 16;
    unsigned short v[4] = {lt[c][cl], lt[c][cl + 1], lt[c][cl + 2], lt[c][cl + 3]};
    *reinterpret_cast<uint2*>(&O[(long)(c0 + c) * inRows + r0 + cl]) =
        *reinterpret_cast<uint2*>(&v[0]);
  }
}

// -------- bf16 MFMA GEMM, 128x128 tile, BK=32, m97 structure + slot swizzle --------
// MODE 0 (K3): weff[b,j,c] = rsum[j] * sum_i st[b,j,i] * vwT[c,i]^T  -> bf16 out
// MODE 1 (K4): out[b,j,n]  = sum_c weff[b,j,c] * xbT[b,n,c]^T + attbias[j] -> f32 out
template <int MODE>
__global__ __launch_bounds__(256) void mfma_nt(const unsigned short* __restrict__ Abase,
                                               const unsigned short* __restrict__ Bbase,
                                               const float* __restrict__ rowscale,
                                               unsigned short* __restrict__ Wout,
                                               float* __restrict__ Fout) {
  __shared__ unsigned short As[128 * 32];
  __shared__ unsigned short Bs[128 * 32];
  const int t = threadIdx.x;
  const int l = t & 63;
  const int w = t >> 6;
  const int wr = w >> 1, wc = w & 1;
  const int b = blockIdx.z;
  const int mBase = blockIdx.y * 128;
  const int nBase = blockIdx.x * 128;

  const unsigned short* Ag = Abase + (long)b * (512 * 512);
  const unsigned short* Bg = Bbase + ((MODE == 0) ? 0L : (long)b * (1024 * 512));

  f32x4 acc[4][4];
#pragma unroll
  for (int i = 0; i < 4; ++i)
#pragma unroll
    for (int j = 0; j < 4; ++j) acc[i][j] = (f32x4){0.f, 0.f, 0.f, 0.f};

  // swizzled ds_read lane offset (ushort units): row-part + slot-part
  const int frag_off = (l & 15) * 32 + (((l >> 4) ^ (l & 3)) * 8);

  for (int k0 = 0; k0 < 512; k0 += BK) {
    __syncthreads();
#pragma unroll
    for (int c = 0; c < 2; ++c) {
      int ch = c * 4 + w;
      int row = ch * 16 + (l >> 2);
      int slot = (l & 3) ^ ((l >> 2) & 3);
      gld_lds16(Ag + (long)(mBase + row) * 512 + k0 + slot * 8, As + ch * 512);
      gld_lds16(Bg + (long)(nBase + row) * 512 + k0 + slot * 8, Bs + ch * 512);
    }
    __syncthreads();
    bf16x8 af[4], bfr[4];
#pragma unroll
    for (int m = 0; m < 4; ++m)
      af[m] = *reinterpret_cast<const bf16x8*>(&As[(wr * 64 + m * 16) * 32 + frag_off]);
#pragma unroll
    for (int n = 0; n < 4; ++n)
      bfr[n] = *reinterpret_cast<const bf16x8*>(&Bs[(wc * 64 + n * 16) * 32 + frag_off]);
#pragma unroll
    for (int m = 0; m < 4; ++m)
#pragma unroll
      for (int n = 0; n < 4; ++n)
        acc[m][n] = __builtin_amdgcn_mfma_f32_16x16x32_bf16(af[m], bfr[n], acc[m][n], 0, 0, 0);
  }

  if (MODE == 0) {
    unsigned short* W = Wout + (long)b * (512 * 512);
#pragma unroll
    for (int m = 0; m < 4; ++m) {
#pragma unroll
      for (int reg = 0; reg < 4; ++reg) {
        int j = mBase + wr * 64 + m * 16 + (l >> 4) * 4 + reg;
        float rs = rowscale[b * 512 + j];
#pragma unroll
        for (int n = 0; n < 4; ++n) {
          int cidx = nBase + wc * 64 + n * 16 + (l & 15);
          W[(long)j * 512 + cidx] = f2bf(acc[m][n][reg] * rs);
        }
      }
    }
  } else {
    float* O = Fout + (long)b * (512 * 1024);
#pragma unroll
    for (int m = 0; m < 4; ++m) {
#pragma unroll
      for (int reg = 0; reg < 4; ++reg) {
        int j = mBase + wr * 64 + m * 16 + (l >> 4) * 4 + reg;
        float ab = rowscale[b * 512 + j];
#pragma unroll
        for (int n = 0; n < 4; ++n) {
          int nidx = nBase + wc * 64 + n * 16 + (l & 15);
          O[(long)j * 1024 + nidx] = acc[m][n][reg] + ab;
        }
      }
    }
  }
}

extern "C" void kernel_launch(void* const* d_in, const int* in_sizes, int n_in,
                              void* d_out, int out_size, void* d_ws, size_t ws_size,
                              hipStream_t stream) {
  const float* x  = (const float*)d_in[0];
  const float* Qm = (const float*)d_in[1];
  const float* Km = (const float*)d_in[2];
  const float* vw = (const float*)d_in[3];
  const float* vb = (const float*)d_in[4];
  float* out = (float*)d_out;

  float* ws = (float*)d_ws;
  float* qk = ws;                                                     // 4,194,304 f
  unsigned short* st   = (unsigned short*)(ws + 4194304);             // 16.7M ush (8,388,608 f)
  unsigned short* weff = (unsigned short*)(ws + 4194304 + 8388608);   // 16.7M ush
  unsigned short* xbT  = (unsigned short*)(ws + 4194304 + 16777216);  // 33.5M ush (16,777,216 f)
  unsigned short* vwT  = (unsigned short*)(ws + 4194304 + 33554432);  // 262,144 ush (131,072 f)
  float* rsum    = ws + 4194304 + 33554432 + 131072;                  // 32,768 f
  float* attbias = rsum + 32768;                                      // 32,768 f
  // total: 37,945,344 floats = 144.8 MiB

  // T1: xbT[b][n][c] = bf16(x[b][c][n])
  transpose_conv<<<dim3(16, 8, 64), 256, 0, stream>>>(x, xbT, 512, 1024, 524288L, 524288L);
  // T2: vwT[c][i] = bf16(vw[i][c])
  transpose_conv<<<dim3(8, 8, 1), 256, 0, stream>>>(vw, vwT, 512, 512, 0L, 0L);
  // K1: qk = xf @ [Qm|Km]
  k1_qk<<<256, 256, 0, stream>>>(x, Qm, Km, qk);
  // K2a: st[b,j,i] = exp(sigmoid(k_j . q_i)), bf16
  k2a_energy<<<1024, 256, 0, stream>>>(qk, st);
  // K2b: rsum, attbias
  k2b_rsum<<<8192, 256, 0, stream>>>(st, vb, rsum, attbias);
  // K3: weff = diag(rsum) . st . Vw   (A=st[j][i], B=vwT[c][i] as [i][c])
  mfma_nt<0><<<dim3(4, 4, 64), 256, 0, stream>>>(st, vwT, rsum, weff, nullptr);
  // K4: out = weff . xf + attbias     (A=weff[j][c], B=xbT[n][c] as [c][n])
  mfma_nt<1><<<dim3(8, 4, 64), 256, 0, stream>>>(weff, xbT, attbias, nullptr, out);
}

// Round 3
// 240.004 us; speedup vs baseline: 3.3688x; 1.3749x over previous
//
#include <hip/hip_runtime.h>

#define TILE 128
#define BK 32
#define LDSS 132

typedef __attribute__((ext_vector_type(8))) short bf16x8;
typedef __attribute__((ext_vector_type(4))) float f32x4;

__device__ __forceinline__ unsigned short f2bf(float f) {
  unsigned u = __builtin_bit_cast(unsigned, f);
  unsigned r = (u + 0x7FFFu + ((u >> 16) & 1u)) >> 16;
  return (unsigned short)r;
}
__device__ __forceinline__ float bf2f(unsigned short h) {
  return __builtin_bit_cast(float, (unsigned)h << 16);
}
__device__ __forceinline__ unsigned pack2(unsigned short a, unsigned short b) {
  return (unsigned)a | ((unsigned)b << 16);
}

__device__ __forceinline__ void gld_lds16(const void* g, void* l) {
  __builtin_amdgcn_global_load_lds(
      (const __attribute__((address_space(1))) unsigned int*)g,
      (__attribute__((address_space(3))) unsigned int*)l, 16, 0, 0);
}

// -------- fp32 8x8 micro-kernel (K2a) --------
__device__ __forceinline__ void micro_mm(const float* As, const float* Bs,
                                         int tr, int tc, float acc[8][8]) {
#pragma unroll
  for (int kk = 0; kk < BK; ++kk) {
    float4 a0 = *reinterpret_cast<const float4*>(&As[kk * LDSS + tr * 4]);
    float4 a1 = *reinterpret_cast<const float4*>(&As[kk * LDSS + 64 + tr * 4]);
    float4 b0 = *reinterpret_cast<const float4*>(&Bs[kk * LDSS + tc * 4]);
    float4 b1 = *reinterpret_cast<const float4*>(&Bs[kk * LDSS + 64 + tc * 4]);
    float a[8] = {a0.x, a0.y, a0.z, a0.w, a1.x, a1.y, a1.z, a1.w};
    float b[8] = {b0.x, b0.y, b0.z, b0.w, b1.x, b1.y, b1.z, b1.w};
#pragma unroll
    for (int i = 0; i < 8; ++i)
#pragma unroll
      for (int j = 0; j < 8; ++j)
        acc[i][j] = fmaf(a[i], b[j], acc[i][j]);
  }
}

__device__ __forceinline__ int row_of(int tr, int i) {
  return (i < 4) ? (tr * 4 + i) : (64 + tr * 4 + (i - 4));
}

// -------- QB prep: Th/Tl[n][k] = split-bf16 of [Qm | Km] column n --------
__global__ __launch_bounds__(256) void qkm_split(const float* __restrict__ Qm,
                                                 const float* __restrict__ Km,
                                                 unsigned short* __restrict__ Th,
                                                 unsigned short* __restrict__ Tl) {
  __shared__ float lt[64][65];
  int k0 = blockIdx.x * 64;
  int half = blockIdx.y;  // 0 -> Qm, 1 -> Km
  const float* M = half ? Km : Qm;
  int t = threadIdx.x;
  int cl = (t & 15) * 4;
  int rl = t >> 4;
#pragma unroll
  for (int rr = 0; rr < 4; ++rr) {
    int r = rl + rr * 16;
    float4 v = *reinterpret_cast<const float4*>(&M[(long)(k0 + r) * 64 + cl]);
    lt[cl + 0][r] = v.x;
    lt[cl + 1][r] = v.y;
    lt[cl + 2][r] = v.z;
    lt[cl + 3][r] = v.w;
  }
  __syncthreads();
#pragma unroll
  for (int rr = 0; rr < 4; ++rr) {
    int c = rl + rr * 16;  // source col = output row
    unsigned short h[4], lo[4];
#pragma unroll
    for (int i = 0; i < 4; ++i) {
      float f = lt[c][cl + i];
      h[i] = f2bf(f);
      lo[i] = f2bf(f - bf2f(h[i]));
    }
    uint2 hv = make_uint2(pack2(h[0], h[1]), pack2(h[2], h[3]));
    uint2 lv = make_uint2(pack2(lo[0], lo[1]), pack2(lo[2], lo[3]));
    *reinterpret_cast<uint2*>(&Th[(long)(half * 64 + c) * 1024 + k0 + cl]) = hv;
    *reinterpret_cast<uint2*>(&Tl[(long)(half * 64 + c) * 1024 + k0 + cl]) = lv;
  }
}

// -------- K1: qk[32768,128] = x[32768,1024] @ [Qm|Km] via split-bf16 MFMA --------
// A (x) reg-staged with in-register hi/lo split; B pre-split via qkm_split.
__global__ __launch_bounds__(256) void k1_mfma(const float* __restrict__ x,
                                               const unsigned short* __restrict__ Th,
                                               const unsigned short* __restrict__ Tl,
                                               float* __restrict__ qk) {
  __shared__ unsigned short Ah[64 * 32];
  __shared__ unsigned short Al[64 * 32];
  __shared__ unsigned short Bh[128 * 32];
  __shared__ unsigned short Bl[128 * 32];
  const int t = threadIdx.x;
  const int l = t & 63;
  const int w = t >> 6;
  const int wr = w >> 1, wc = w & 1;
  const long mBase = (long)blockIdx.x * 64;

  f32x4 acc[2][4];
#pragma unroll
  for (int m = 0; m < 2; ++m)
#pragma unroll
    for (int n = 0; n < 4; ++n) acc[m][n] = (f32x4){0.f, 0.f, 0.f, 0.f};

  const int arow = t >> 2;                       // 0..63
  const int ak = (t & 3) * 8;                    // fp32 k-offset within BK
  const int aslot = (t & 3) ^ (arow & 3);        // swizzled LDS slot
  const int bslot = (l & 3) ^ ((l >> 2) & 3);    // swizzled global slot for gld_lds
  const int frag_off = (l & 15) * 32 + (((l >> 4) ^ (l & 3)) * 8);
  const float* xrow = x + (mBase + arow) * 1024;

  for (int k0 = 0; k0 < 1024; k0 += BK) {
    // A: issue fp32 loads early (latency hides under previous MFMA phase)
    float4 xa0 = *reinterpret_cast<const float4*>(&xrow[k0 + ak]);
    float4 xa1 = *reinterpret_cast<const float4*>(&xrow[k0 + ak + 4]);
    __syncthreads();
    // B: global_load_lds width-16, swizzled source
#pragma unroll
    for (int c = 0; c < 2; ++c) {
      int br = w * 32 + c * 16 + (l >> 2);
      gld_lds16(Th + (long)br * 1024 + k0 + bslot * 8, Bh + (w * 32 + c * 16) * 32);
      gld_lds16(Tl + (long)br * 1024 + k0 + bslot * 8, Bl + (w * 32 + c * 16) * 32);
    }
    // A: split to hi/lo in registers, swizzled ds_write_b128
    float f[8] = {xa0.x, xa0.y, xa0.z, xa0.w, xa1.x, xa1.y, xa1.z, xa1.w};
    unsigned short hh[8], ll[8];
#pragma unroll
    for (int i = 0; i < 8; ++i) {
      hh[i] = f2bf(f[i]);
      ll[i] = f2bf(f[i] - bf2f(hh[i]));
    }
    uint4 hv = make_uint4(pack2(hh[0], hh[1]), pack2(hh[2], hh[3]),
                          pack2(hh[4], hh[5]), pack2(hh[6], hh[7]));
    uint4 lv = make_uint4(pack2(ll[0], ll[1]), pack2(ll[2], ll[3]),
                          pack2(ll[4], ll[5]), pack2(ll[6], ll[7]));
    *reinterpret_cast<uint4*>(&Ah[arow * 32 + aslot * 8]) = hv;
    *reinterpret_cast<uint4*>(&Al[arow * 32 + aslot * 8]) = lv;
    __syncthreads();

    bf16x8 ah[2], alo[2], bh[4], blo[4];
#pragma unroll
    for (int m = 0; m < 2; ++m) {
      ah[m] = *reinterpret_cast<const bf16x8*>(&Ah[(wr * 32 + m * 16) * 32 + frag_off]);
      alo[m] = *reinterpret_cast<const bf16x8*>(&Al[(wr * 32 + m * 16) * 32 + frag_off]);
    }
#pragma unroll
    for (int n = 0; n < 4; ++n) {
      bh[n] = *reinterpret_cast<const bf16x8*>(&Bh[(wc * 64 + n * 16) * 32 + frag_off]);
      blo[n] = *reinterpret_cast<const bf16x8*>(&Bl[(wc * 64 + n * 16) * 32 + frag_off]);
    }
#pragma unroll
    for (int m = 0; m < 2; ++m)
#pragma unroll
      for (int n = 0; n < 4; ++n) {
        acc[m][n] = __builtin_amdgcn_mfma_f32_16x16x32_bf16(ah[m], bh[n], acc[m][n], 0, 0, 0);
        acc[m][n] = __builtin_amdgcn_mfma_f32_16x16x32_bf16(ah[m], blo[n], acc[m][n], 0, 0, 0);
        acc[m][n] = __builtin_amdgcn_mfma_f32_16x16x32_bf16(alo[m], bh[n], acc[m][n], 0, 0, 0);
      }
  }
#pragma unroll
  for (int m = 0; m < 2; ++m)
#pragma unroll
    for (int reg = 0; reg < 4; ++reg) {
      long row = mBase + wr * 32 + m * 16 + (l >> 4) * 4 + reg;
#pragma unroll
      for (int n = 0; n < 4; ++n)
        qk[row * 128 + wc * 64 + n * 16 + (l & 15)] = acc[m][n][reg];
    }
}

// -------- K2a: st[b,j,i] = exp(sigmoid(k_j . q_i))  (fp32 compute, bf16 out) --------
__global__ __launch_bounds__(256) void k2a_energy(const float* __restrict__ qk,
                                                  unsigned short* __restrict__ st) {
  __shared__ float As[BK * LDSS];
  __shared__ float Bs[BK * LDSS];
  int t = threadIdx.x;
  int tc = t & 15, tr = t >> 4;
  int b = blockIdx.x >> 4;
  int jBase = ((blockIdx.x >> 2) & 3) * TILE;
  int iBase = (blockIdx.x & 3) * TILE;
  const float* qb = qk + (long)b * 512 * 128;
  float acc[8][8] = {};

  for (int d0 = 0; d0 < 64; d0 += BK) {
#pragma unroll
    for (int r = 0; r < 4; ++r) {
      int rl = (t >> 3) + 32 * r;
      int d = (t & 7) * 4;
      float4 va = *reinterpret_cast<const float4*>(&qb[(long)(jBase + rl) * 128 + 64 + d0 + d]);
      As[(d + 0) * LDSS + rl] = va.x;
      As[(d + 1) * LDSS + rl] = va.y;
      As[(d + 2) * LDSS + rl] = va.z;
      As[(d + 3) * LDSS + rl] = va.w;
      float4 vk = *reinterpret_cast<const float4*>(&qb[(long)(iBase + rl) * 128 + d0 + d]);
      Bs[(d + 0) * LDSS + rl] = vk.x;
      Bs[(d + 1) * LDSS + rl] = vk.y;
      Bs[(d + 2) * LDSS + rl] = vk.z;
      Bs[(d + 3) * LDSS + rl] = vk.w;
    }
    __syncthreads();
    micro_mm(As, Bs, tr, tc, acc);
    __syncthreads();
  }
  unsigned short* sb = st + (long)b * 512 * 512;
#pragma unroll
  for (int i = 0; i < 8; ++i) {
    int row = jBase + row_of(tr, i);
    unsigned short v[8];
#pragma unroll
    for (int j = 0; j < 8; ++j) {
      float sg = 1.0f / (1.0f + __expf(-acc[i][j]));
      v[j] = f2bf(__expf(sg));
    }
    *reinterpret_cast<uint2*>(&sb[(long)row * 512 + iBase + tc * 4]) =
        *reinterpret_cast<uint2*>(&v[0]);
    *reinterpret_cast<uint2*>(&sb[(long)row * 512 + iBase + 64 + tc * 4]) =
        *reinterpret_cast<uint2*>(&v[4]);
  }
}

// -------- K2b: per-row (j) sums of st -> rsum = 1/sum, attbias = (st.bias)/sum --------
__global__ __launch_bounds__(256) void k2b_rsum(const unsigned short* __restrict__ st,
                                                const float* __restrict__ bias,
                                                float* __restrict__ rsum,
                                                float* __restrict__ attbias) {
  int jg = blockIdx.x * 4 + (threadIdx.x >> 6);
  int l = threadIdx.x & 63;
  const unsigned short* row = st + (long)jg * 512 + l * 8;
  ushort4 u0 = *reinterpret_cast<const ushort4*>(row);
  ushort4 u1 = *reinterpret_cast<const ushort4*>(row + 4);
  float4 b0 = *reinterpret_cast<const float4*>(&bias[l * 8]);
  float4 b1 = *reinterpret_cast<const float4*>(&bias[l * 8 + 4]);
  float f0 = bf2f(u0.x), f1 = bf2f(u0.y), f2 = bf2f(u0.z), f3 = bf2f(u0.w);
  float f4 = bf2f(u1.x), f5 = bf2f(u1.y), f6 = bf2f(u1.z), f7 = bf2f(u1.w);
  float sum = (f0 + f1) + (f2 + f3) + ((f4 + f5) + (f6 + f7));
  float sumb = f0 * b0.x + f1 * b0.y + f2 * b0.z + f3 * b0.w +
               f4 * b1.x + f5 * b1.y + f6 * b1.z + f7 * b1.w;
#pragma unroll
  for (int off = 32; off > 0; off >>= 1) {
    sum += __shfl_down(sum, off);
    sumb += __shfl_down(sumb, off);
  }
  if (l == 0) {
    float r = 1.0f / sum;
    rsum[jg] = r;
    attbias[jg] = sumb * r;
  }
}

// -------- transpose + fp32->bf16 convert: out[c][r] = bf16(in[r][c]), 64x64 tiles ----
__global__ __launch_bounds__(256) void transpose_conv(const float* __restrict__ in,
                                                      unsigned short* __restrict__ out,
                                                      int inRows, int inCols,
                                                      long inBatch, long outBatch) {
  __shared__ unsigned short lt[64][65];
  int b = blockIdx.z;
  int r0 = blockIdx.y * 64;
  int c0 = blockIdx.x * 64;
  const float* I = in + (long)b * inBatch;
  unsigned short* O = out + (long)b * outBatch;
  int t = threadIdx.x;
  int cl = (t & 15) * 4;
  int rl = t >> 4;
#pragma unroll
  for (int rr = 0; rr < 4; ++rr) {
    int r = rl + rr * 16;
    float4 v = *reinterpret_cast<const float4*>(&I[(long)(r0 + r) * inCols + c0 + cl]);
    lt[cl + 0][r] = f2bf(v.x);
    lt[cl + 1][r] = f2bf(v.y);
    lt[cl + 2][r] = f2bf(v.z);
    lt[cl + 3][r] = f2bf(v.w);
  }
  __syncthreads();
#pragma unroll
  for (int rr = 0; rr < 4; ++rr) {
    int c = rl + rr * 16;
    unsigned short v[4] = {lt[c][cl], lt[c][cl + 1], lt[c][cl + 2], lt[c][cl + 3]};
    *reinterpret_cast<uint2*>(&O[(long)(c0 + c) * inRows + r0 + cl]) =
        *reinterpret_cast<uint2*>(&v[0]);
  }
}

// -------- bf16 MFMA GEMM, 128x128 tile, BK=32, m97 structure + slot swizzle --------
template <int MODE>
__global__ __launch_bounds__(256) void mfma_nt(const unsigned short* __restrict__ Abase,
                                               const unsigned short* __restrict__ Bbase,
                                               const float* __restrict__ rowscale,
                                               unsigned short* __restrict__ Wout,
                                               float* __restrict__ Fout) {
  __shared__ unsigned short As[128 * 32];
  __shared__ unsigned short Bs[128 * 32];
  const int t = threadIdx.x;
  const int l = t & 63;
  const int w = t >> 6;
  const int wr = w >> 1, wc = w & 1;
  const int b = blockIdx.z;
  const int mBase = blockIdx.y * 128;
  const int nBase = blockIdx.x * 128;

  const unsigned short* Ag = Abase + (long)b * (512 * 512);
  const unsigned short* Bg = Bbase + ((MODE == 0) ? 0L : (long)b * (1024 * 512));

  f32x4 acc[4][4];
#pragma unroll
  for (int i = 0; i < 4; ++i)
#pragma unroll
    for (int j = 0; j < 4; ++j) acc[i][j] = (f32x4){0.f, 0.f, 0.f, 0.f};

  const int frag_off = (l & 15) * 32 + (((l >> 4) ^ (l & 3)) * 8);

  for (int k0 = 0; k0 < 512; k0 += BK) {
    __syncthreads();
#pragma unroll
    for (int c = 0; c < 2; ++c) {
      int ch = c * 4 + w;
      int row = ch * 16 + (l >> 2);
      int slot = (l & 3) ^ ((l >> 2) & 3);
      gld_lds16(Ag + (long)(mBase + row) * 512 + k0 + slot * 8, As + ch * 512);
      gld_lds16(Bg + (long)(nBase + row) * 512 + k0 + slot * 8, Bs + ch * 512);
    }
    __syncthreads();
    bf16x8 af[4], bfr[4];
#pragma unroll
    for (int m = 0; m < 4; ++m)
      af[m] = *reinterpret_cast<const bf16x8*>(&As[(wr * 64 + m * 16) * 32 + frag_off]);
#pragma unroll
    for (int n = 0; n < 4; ++n)
      bfr[n] = *reinterpret_cast<const bf16x8*>(&Bs[(wc * 64 + n * 16) * 32 + frag_off]);
#pragma unroll
    for (int m = 0; m < 4; ++m)
#pragma unroll
      for (int n = 0; n < 4; ++n)
        acc[m][n] = __builtin_amdgcn_mfma_f32_16x16x32_bf16(af[m], bfr[n], acc[m][n], 0, 0, 0);
  }

  if (MODE == 0) {
    unsigned short* W = Wout + (long)b * (512 * 512);
#pragma unroll
    for (int m = 0; m < 4; ++m) {
#pragma unroll
      for (int reg = 0; reg < 4; ++reg) {
        int j = mBase + wr * 64 + m * 16 + (l >> 4) * 4 + reg;
        float rs = rowscale[b * 512 + j];
#pragma unroll
        for (int n = 0; n < 4; ++n) {
          int cidx = nBase + wc * 64 + n * 16 + (l & 15);
          W[(long)j * 512 + cidx] = f2bf(acc[m][n][reg] * rs);
        }
      }
    }
  } else {
    float* O = Fout + (long)b * (512 * 1024);
#pragma unroll
    for (int m = 0; m < 4; ++m) {
#pragma unroll
      for (int reg = 0; reg < 4; ++reg) {
        int j = mBase + wr * 64 + m * 16 + (l >> 4) * 4 + reg;
        float ab = rowscale[b * 512 + j];
#pragma unroll
        for (int n = 0; n < 4; ++n) {
          int nidx = nBase + wc * 64 + n * 16 + (l & 15);
          O[(long)j * 1024 + nidx] = acc[m][n][reg] + ab;
        }
      }
    }
  }
}

extern "C" void kernel_launch(void* const* d_in, const int* in_sizes, int n_in,
                              void* d_out, int out_size, void* d_ws, size_t ws_size,
                              hipStream_t stream) {
  const float* x  = (const float*)d_in[0];
  const float* Qm = (const float*)d_in[1];
  const float* Km = (const float*)d_in[2];
  const float* vw = (const float*)d_in[3];
  const float* vb = (const float*)d_in[4];
  float* out = (float*)d_out;

  float* ws = (float*)d_ws;
  float* qk = ws;                                                     // 4,194,304 f
  unsigned short* st   = (unsigned short*)(ws + 4194304);             // spans 8,388,608 f
  unsigned short* weff = (unsigned short*)(ws + 4194304 + 8388608);   // spans 8,388,608 f
  unsigned short* xbT  = (unsigned short*)(ws + 4194304 + 16777216);  // spans 16,777,216 f
  unsigned short* vwT  = (unsigned short*)(ws + 4194304 + 33554432);  // spans 131,072 f
  unsigned short* qkTh = (unsigned short*)(ws + 4194304 + 33554432 + 131072);  // 65,536 f
  unsigned short* qkTl = qkTh + 131072;                               // 65,536 f
  float* rsum    = ws + 4194304 + 33554432 + 131072 + 131072;         // 32,768 f
  float* attbias = rsum + 32768;                                      // 32,768 f
  // total: 38,076,416 floats ≈ 145.3 MiB

  // T1: xbT[b][n][c] = bf16(x[b][c][n])
  transpose_conv<<<dim3(16, 8, 64), 256, 0, stream>>>(x, xbT, 512, 1024, 524288L, 524288L);
  // T2: vwT[c][i] = bf16(vw[i][c])
  transpose_conv<<<dim3(8, 8, 1), 256, 0, stream>>>(vw, vwT, 512, 512, 0L, 0L);
  // T3: split-transposed [Qm|Km] -> qkTh/qkTl [128][1024]
  qkm_split<<<dim3(16, 2), 256, 0, stream>>>(Qm, Km, qkTh, qkTl);
  // K1: qk = x @ [Qm|Km], split-bf16 MFMA
  k1_mfma<<<512, 256, 0, stream>>>(x, qkTh, qkTl, qk);
  // K2a: st[b,j,i] = exp(sigmoid(k_j . q_i)), bf16
  k2a_energy<<<1024, 256, 0, stream>>>(qk, st);
  // K2b: rsum, attbias
  k2b_rsum<<<8192, 256, 0, stream>>>(st, vb, rsum, attbias);
  // K3: weff = diag(rsum) . st . Vw
  mfma_nt<0><<<dim3(4, 4, 64), 256, 0, stream>>>(st, vwT, rsum, weff, nullptr);
  // K4: out = weff . xf + attbias
  mfma_nt<1><<<dim3(8, 4, 64), 256, 0, stream>>>(weff, xbT, attbias, nullptr, out);
}

// Round 4
// 231.780 us; speedup vs baseline: 3.4883x; 1.0355x over previous
//
#include <hip/hip_runtime.h>

#define BK 32

typedef __attribute__((ext_vector_type(8))) short bf16x8;
typedef __attribute__((ext_vector_type(4))) float f32x4;

__device__ __forceinline__ unsigned short f2bf(float f) {
  unsigned u = __builtin_bit_cast(unsigned, f);
  unsigned r = (u + 0x7FFFu + ((u >> 16) & 1u)) >> 16;
  return (unsigned short)r;
}
__device__ __forceinline__ float bf2f(unsigned short h) {
  return __builtin_bit_cast(float, (unsigned)h << 16);
}
__device__ __forceinline__ unsigned pack2(unsigned short a, unsigned short b) {
  return (unsigned)a | ((unsigned)b << 16);
}

__device__ __forceinline__ void gld_lds16(const void* g, void* l) {
  __builtin_amdgcn_global_load_lds(
      (const __attribute__((address_space(1))) unsigned int*)g,
      (__attribute__((address_space(3))) unsigned int*)l, 16, 0, 0);
}

// split 8 fp32 -> hi/lo bf16, store as uint4 pair (ds_write_b128)
__device__ __forceinline__ void split8_store(float4 v0, float4 v1,
                                             unsigned short* Hdst,
                                             unsigned short* Ldst) {
  float f[8] = {v0.x, v0.y, v0.z, v0.w, v1.x, v1.y, v1.z, v1.w};
  unsigned short hh[8], ll[8];
#pragma unroll
  for (int i = 0; i < 8; ++i) {
    hh[i] = f2bf(f[i]);
    ll[i] = f2bf(f[i] - bf2f(hh[i]));
  }
  *reinterpret_cast<uint4*>(Hdst) = make_uint4(pack2(hh[0], hh[1]), pack2(hh[2], hh[3]),
                                               pack2(hh[4], hh[5]), pack2(hh[6], hh[7]));
  *reinterpret_cast<uint4*>(Ldst) = make_uint4(pack2(ll[0], ll[1]), pack2(ll[2], ll[3]),
                                               pack2(ll[4], ll[5]), pack2(ll[6], ll[7]));
}

// -------- QB prep: Th/Tl[d][k] = split-bf16 of [Qm | Km] column d --------
__global__ __launch_bounds__(256) void qkm_split(const float* __restrict__ Qm,
                                                 const float* __restrict__ Km,
                                                 unsigned short* __restrict__ Th,
                                                 unsigned short* __restrict__ Tl) {
  __shared__ float lt[64][65];
  int k0 = blockIdx.x * 64;
  int half = blockIdx.y;
  const float* M = half ? Km : Qm;
  int t = threadIdx.x;
  int cl = (t & 15) * 4;
  int rl = t >> 4;
#pragma unroll
  for (int rr = 0; rr < 4; ++rr) {
    int r = rl + rr * 16;
    float4 v = *reinterpret_cast<const float4*>(&M[(long)(k0 + r) * 64 + cl]);
    lt[cl + 0][r] = v.x;
    lt[cl + 1][r] = v.y;
    lt[cl + 2][r] = v.z;
    lt[cl + 3][r] = v.w;
  }
  __syncthreads();
#pragma unroll
  for (int rr = 0; rr < 4; ++rr) {
    int c = rl + rr * 16;
    unsigned short h[4], lo[4];
#pragma unroll
    for (int i = 0; i < 4; ++i) {
      float f = lt[c][cl + i];
      h[i] = f2bf(f);
      lo[i] = f2bf(f - bf2f(h[i]));
    }
    *reinterpret_cast<uint2*>(&Th[(long)(half * 64 + c) * 1024 + k0 + cl]) =
        make_uint2(pack2(h[0], h[1]), pack2(h[2], h[3]));
    *reinterpret_cast<uint2*>(&Tl[(long)(half * 64 + c) * 1024 + k0 + cl]) =
        make_uint2(pack2(lo[0], lo[1]), pack2(lo[2], lo[3]));
  }
}

// -------- K1: qk[32768,128] = x @ [Qm|Km], split-bf16 MFMA, A=d-rows B=x-rows ----
__global__ __launch_bounds__(256) void k1_mfma(const float* __restrict__ x,
                                               const unsigned short* __restrict__ Th,
                                               const unsigned short* __restrict__ Tl,
                                               float* __restrict__ qk) {
  __shared__ unsigned short Dh[128 * 32];
  __shared__ unsigned short Dl[128 * 32];
  __shared__ unsigned short Xh[64 * 32];
  __shared__ unsigned short Xl[64 * 32];
  const int t = threadIdx.x;
  const int l = t & 63;
  const int w = t >> 6;
  const int wr = w >> 1, wc = w & 1;  // wr: d-half (2x64), wc: x-half (2x32)
  const long mBase = (long)blockIdx.x * 64;

  f32x4 acc[4][2];
#pragma unroll
  for (int m = 0; m < 4; ++m)
#pragma unroll
    for (int n = 0; n < 2; ++n) acc[m][n] = (f32x4){0.f, 0.f, 0.f, 0.f};

  const int xrow_l = t >> 2;
  const int kslot = t & 3;
  const int xsl = kslot ^ ((t >> 3) & 3);          // f(row)=(row>>1)&3, row=t>>2
  const int srcslot = (l & 3) ^ ((l >> 3) & 3);    // gld_lds source k-slot
  const int frag_off = (l & 15) * 32 + ((((l >> 4) ^ (l >> 1)) & 3) * 8);
  const float* xrow = x + (mBase + xrow_l) * 1024;

  for (int k0 = 0; k0 < 1024; k0 += BK) {
    float4 xa0 = *reinterpret_cast<const float4*>(&xrow[k0 + kslot * 8]);
    float4 xa1 = *reinterpret_cast<const float4*>(&xrow[k0 + kslot * 8 + 4]);
    __syncthreads();
#pragma unroll
    for (int c = 0; c < 2; ++c) {
      int ch = c * 4 + w;
      int row = ch * 16 + (l >> 2);
      gld_lds16(Th + (long)row * 1024 + k0 + srcslot * 8, Dh + ch * 512);
      gld_lds16(Tl + (long)row * 1024 + k0 + srcslot * 8, Dl + ch * 512);
    }
    split8_store(xa0, xa1, &Xh[xrow_l * 32 + xsl * 8], &Xl[xrow_l * 32 + xsl * 8]);
    __syncthreads();

    bf16x8 dh[4], dl[4], xh[2], xl[2];
#pragma unroll
    for (int m = 0; m < 4; ++m) {
      dh[m] = *reinterpret_cast<const bf16x8*>(&Dh[(wr * 64 + m * 16) * 32 + frag_off]);
      dl[m] = *reinterpret_cast<const bf16x8*>(&Dl[(wr * 64 + m * 16) * 32 + frag_off]);
    }
#pragma unroll
    for (int n = 0; n < 2; ++n) {
      xh[n] = *reinterpret_cast<const bf16x8*>(&Xh[(wc * 32 + n * 16) * 32 + frag_off]);
      xl[n] = *reinterpret_cast<const bf16x8*>(&Xl[(wc * 32 + n * 16) * 32 + frag_off]);
    }
#pragma unroll
    for (int m = 0; m < 4; ++m)
#pragma unroll
      for (int n = 0; n < 2; ++n) {
        acc[m][n] = __builtin_amdgcn_mfma_f32_16x16x32_bf16(dh[m], xh[n], acc[m][n], 0, 0, 0);
        acc[m][n] = __builtin_amdgcn_mfma_f32_16x16x32_bf16(dh[m], xl[n], acc[m][n], 0, 0, 0);
        acc[m][n] = __builtin_amdgcn_mfma_f32_16x16x32_bf16(dl[m], xh[n], acc[m][n], 0, 0, 0);
      }
  }
#pragma unroll
  for (int m = 0; m < 4; ++m)
#pragma unroll
    for (int n = 0; n < 2; ++n) {
      int d0 = wr * 64 + m * 16 + (l >> 4) * 4;
      long xr = mBase + wc * 32 + n * 16 + (l & 15);
      *reinterpret_cast<float4*>(&qk[xr * 128 + d0]) =
          make_float4(acc[m][n][0], acc[m][n][1], acc[m][n][2], acc[m][n][3]);
    }
}

// -------- K2a: st[b,j,i] = exp(sigmoid(q_i . k_j)) via split-bf16 MFMA --------
// A = q-rows (i, M-side), B = k-rows (j, N-side); store 4 packed bf16 along i.
__global__ __launch_bounds__(256) void k2a_mfma(const float* __restrict__ qk,
                                                unsigned short* __restrict__ st) {
  __shared__ unsigned short Ah[128 * 32];
  __shared__ unsigned short Al[128 * 32];
  __shared__ unsigned short Bh[128 * 32];
  __shared__ unsigned short Bl[128 * 32];
  const int t = threadIdx.x;
  const int l = t & 63;
  const int w = t >> 6;
  const int wr = w >> 1, wc = w & 1;
  const int b = blockIdx.z;
  const int iBase = blockIdx.y * 128;
  const int jBase = blockIdx.x * 128;
  const float* qb = qk + (long)b * 512 * 128;

  f32x4 acc[4][4];
#pragma unroll
  for (int m = 0; m < 4; ++m)
#pragma unroll
    for (int n = 0; n < 4; ++n) acc[m][n] = (f32x4){0.f, 0.f, 0.f, 0.f};

  const int r0 = t >> 2;
  const int kslot = t & 3;
  const int sl = kslot ^ ((t >> 3) & 3);
  const int frag_off = (l & 15) * 32 + ((((l >> 4) ^ (l >> 1)) & 3) * 8);

  for (int d0 = 0; d0 < 64; d0 += BK) {
    __syncthreads();
#pragma unroll
    for (int h = 0; h < 2; ++h) {
      int row = r0 + h * 64;
      const float* qa = &qb[(long)(iBase + row) * 128 + d0 + kslot * 8];
      float4 a0 = *reinterpret_cast<const float4*>(qa);
      float4 a1 = *reinterpret_cast<const float4*>(qa + 4);
      split8_store(a0, a1, &Ah[row * 32 + sl * 8], &Al[row * 32 + sl * 8]);
      const float* kb = &qb[(long)(jBase + row) * 128 + 64 + d0 + kslot * 8];
      float4 b0 = *reinterpret_cast<const float4*>(kb);
      float4 b1 = *reinterpret_cast<const float4*>(kb + 4);
      split8_store(b0, b1, &Bh[row * 32 + sl * 8], &Bl[row * 32 + sl * 8]);
    }
    __syncthreads();

    bf16x8 ah[4], al4[4], bh[4], bl4[4];
#pragma unroll
    for (int m = 0; m < 4; ++m) {
      ah[m] = *reinterpret_cast<const bf16x8*>(&Ah[(wr * 64 + m * 16) * 32 + frag_off]);
      al4[m] = *reinterpret_cast<const bf16x8*>(&Al[(wr * 64 + m * 16) * 32 + frag_off]);
    }
#pragma unroll
    for (int n = 0; n < 4; ++n) {
      bh[n] = *reinterpret_cast<const bf16x8*>(&Bh[(wc * 64 + n * 16) * 32 + frag_off]);
      bl4[n] = *reinterpret_cast<const bf16x8*>(&Bl[(wc * 64 + n * 16) * 32 + frag_off]);
    }
#pragma unroll
    for (int m = 0; m < 4; ++m)
#pragma unroll
      for (int n = 0; n < 4; ++n) {
        acc[m][n] = __builtin_amdgcn_mfma_f32_16x16x32_bf16(ah[m], bh[n], acc[m][n], 0, 0, 0);
        acc[m][n] = __builtin_amdgcn_mfma_f32_16x16x32_bf16(ah[m], bl4[n], acc[m][n], 0, 0, 0);
        acc[m][n] = __builtin_amdgcn_mfma_f32_16x16x32_bf16(al4[m], bh[n], acc[m][n], 0, 0, 0);
      }
  }
  unsigned short* sb = st + (long)b * 512 * 512;
#pragma unroll
  for (int m = 0; m < 4; ++m)
#pragma unroll
    for (int n = 0; n < 4; ++n) {
      int i0 = iBase + wr * 64 + m * 16 + (l >> 4) * 4;
      int j = jBase + wc * 64 + n * 16 + (l & 15);
      unsigned short p[4];
#pragma unroll
      for (int reg = 0; reg < 4; ++reg) {
        float sg = 1.0f / (1.0f + __expf(-acc[m][n][reg]));
        p[reg] = f2bf(__expf(sg));
      }
      *reinterpret_cast<uint2*>(&sb[(long)j * 512 + i0]) = *reinterpret_cast<uint2*>(p);
    }
}

// -------- K2b: per-row (j) sums of st -> rsum = 1/sum, attbias = (st.bias)/sum ----
__global__ __launch_bounds__(256) void k2b_rsum(const unsigned short* __restrict__ st,
                                                const float* __restrict__ bias,
                                                float* __restrict__ rsum,
                                                float* __restrict__ attbias) {
  int jg = blockIdx.x * 4 + (threadIdx.x >> 6);
  int l = threadIdx.x & 63;
  const unsigned short* row = st + (long)jg * 512 + l * 8;
  ushort4 u0 = *reinterpret_cast<const ushort4*>(row);
  ushort4 u1 = *reinterpret_cast<const ushort4*>(row + 4);
  float4 b0 = *reinterpret_cast<const float4*>(&bias[l * 8]);
  float4 b1 = *reinterpret_cast<const float4*>(&bias[l * 8 + 4]);
  float f0 = bf2f(u0.x), f1 = bf2f(u0.y), f2 = bf2f(u0.z), f3 = bf2f(u0.w);
  float f4 = bf2f(u1.x), f5 = bf2f(u1.y), f6 = bf2f(u1.z), f7 = bf2f(u1.w);
  float sum = (f0 + f1) + (f2 + f3) + ((f4 + f5) + (f6 + f7));
  float sumb = f0 * b0.x + f1 * b0.y + f2 * b0.z + f3 * b0.w +
               f4 * b1.x + f5 * b1.y + f6 * b1.z + f7 * b1.w;
#pragma unroll
  for (int off = 32; off > 0; off >>= 1) {
    sum += __shfl_down(sum, off);
    sumb += __shfl_down(sumb, off);
  }
  if (l == 0) {
    float r = 1.0f / sum;
    rsum[jg] = r;
    attbias[jg] = sumb * r;
  }
}

// -------- transpose + fp32->bf16 convert: out[c][r] = bf16(in[r][c]) --------
__global__ __launch_bounds__(256) void transpose_conv(const float* __restrict__ in,
                                                      unsigned short* __restrict__ out,
                                                      int inRows, int inCols,
                                                      long inBatch, long outBatch) {
  __shared__ unsigned short lt[64][65];
  int b = blockIdx.z;
  int r0 = blockIdx.y * 64;
  int c0 = blockIdx.x * 64;
  const float* I = in + (long)b * inBatch;
  unsigned short* O = out + (long)b * outBatch;
  int t = threadIdx.x;
  int cl = (t & 15) * 4;
  int rl = t >> 4;
#pragma unroll
  for (int rr = 0; rr < 4; ++rr) {
    int r = rl + rr * 16;
    float4 v = *reinterpret_cast<const float4*>(&I[(long)(r0 + r) * inCols + c0 + cl]);
    lt[cl + 0][r] = f2bf(v.x);
    lt[cl + 1][r] = f2bf(v.y);
    lt[cl + 2][r] = f2bf(v.z);
    lt[cl + 3][r] = f2bf(v.w);
  }
  __syncthreads();
#pragma unroll
  for (int rr = 0; rr < 4; ++rr) {
    int c = rl + rr * 16;
    unsigned short v[4] = {lt[c][cl], lt[c][cl + 1], lt[c][cl + 2], lt[c][cl + 3]};
    *reinterpret_cast<uint2*>(&O[(long)(c0 + c) * inRows + r0 + cl]) =
        *reinterpret_cast<uint2*>(&v[0]);
  }
}

// -------- bf16 MFMA GEMM, 128x128 tile, BK=32; A = M-side (store-contiguous dim) ----
// MODE 0 (K3): A=vwT[c][i] (unbatched), B=st[b][j][i]; weff[b,j,c] = rsum[j]*D[c][j]
// MODE 1 (K4): A=xbT[b][n][c], B=weff[b][j][c]; out[b,j,n] = D[n][j] + attbias[j]
template <int MODE>
__global__ __launch_bounds__(256) void mfma_nt(const unsigned short* __restrict__ Abase,
                                               const unsigned short* __restrict__ Bbase,
                                               const float* __restrict__ rowscale,
                                               unsigned short* __restrict__ Wout,
                                               float* __restrict__ Fout) {
  __shared__ unsigned short As[128 * 32];
  __shared__ unsigned short Bs[128 * 32];
  const int t = threadIdx.x;
  const int l = t & 63;
  const int w = t >> 6;
  const int wr = w >> 1, wc = w & 1;
  const int b = blockIdx.z;
  const int mBase = blockIdx.y * 128;
  const int nBase = blockIdx.x * 128;

  const unsigned short* Ag = Abase + ((MODE == 0) ? 0L : (long)b * (1024 * 512)) + (long)mBase * 512;
  const unsigned short* Bg = Bbase + (long)b * (512 * 512) + (long)nBase * 512;

  f32x4 acc[4][4];
#pragma unroll
  for (int i = 0; i < 4; ++i)
#pragma unroll
    for (int j = 0; j < 4; ++j) acc[i][j] = (f32x4){0.f, 0.f, 0.f, 0.f};

  const int srcslot = (l & 3) ^ ((l >> 3) & 3);
  const int frag_off = (l & 15) * 32 + ((((l >> 4) ^ (l >> 1)) & 3) * 8);

  for (int k0 = 0; k0 < 512; k0 += BK) {
    __syncthreads();
#pragma unroll
    for (int c = 0; c < 2; ++c) {
      int ch = c * 4 + w;
      int row = ch * 16 + (l >> 2);
      gld_lds16(Ag + (long)row * 512 + k0 + srcslot * 8, As + ch * 512);
      gld_lds16(Bg + (long)row * 512 + k0 + srcslot * 8, Bs + ch * 512);
    }
    __syncthreads();
    bf16x8 af[4], bfr[4];
#pragma unroll
    for (int m = 0; m < 4; ++m)
      af[m] = *reinterpret_cast<const bf16x8*>(&As[(wr * 64 + m * 16) * 32 + frag_off]);
#pragma unroll
    for (int n = 0; n < 4; ++n)
      bfr[n] = *reinterpret_cast<const bf16x8*>(&Bs[(wc * 64 + n * 16) * 32 + frag_off]);
#pragma unroll
    for (int m = 0; m < 4; ++m)
#pragma unroll
      for (int n = 0; n < 4; ++n)
        acc[m][n] = __builtin_amdgcn_mfma_f32_16x16x32_bf16(af[m], bfr[n], acc[m][n], 0, 0, 0);
  }

  if (MODE == 0) {
    unsigned short* W = Wout + (long)b * (512 * 512);
#pragma unroll
    for (int m = 0; m < 4; ++m)
#pragma unroll
      for (int n = 0; n < 4; ++n) {
        int c0 = mBase + wr * 64 + m * 16 + (l >> 4) * 4;
        int j = nBase + wc * 64 + n * 16 + (l & 15);
        float rs = rowscale[b * 512 + j];
        unsigned short p[4];
#pragma unroll
        for (int reg = 0; reg < 4; ++reg) p[reg] = f2bf(acc[m][n][reg] * rs);
        *reinterpret_cast<uint2*>(&W[(long)j * 512 + c0]) = *reinterpret_cast<uint2*>(p);
      }
  } else {
    float* O = Fout + (long)b * (512 * 1024);
#pragma unroll
    for (int m = 0; m < 4; ++m)
#pragma unroll
      for (int n = 0; n < 4; ++n) {
        int n0 = mBase + wr * 64 + m * 16 + (l >> 4) * 4;
        int j = nBase + wc * 64 + n * 16 + (l & 15);
        float ab = rowscale[b * 512 + j];
        *reinterpret_cast<float4*>(&O[(long)j * 1024 + n0]) =
            make_float4(acc[m][n][0] + ab, acc[m][n][1] + ab,
                        acc[m][n][2] + ab, acc[m][n][3] + ab);
      }
  }
}

extern "C" void kernel_launch(void* const* d_in, const int* in_sizes, int n_in,
                              void* d_out, int out_size, void* d_ws, size_t ws_size,
                              hipStream_t stream) {
  const float* x  = (const float*)d_in[0];
  const float* Qm = (const float*)d_in[1];
  const float* Km = (const float*)d_in[2];
  const float* vw = (const float*)d_in[3];
  const float* vb = (const float*)d_in[4];
  float* out = (float*)d_out;

  float* ws = (float*)d_ws;
  float* qk = ws;                                                     // 4,194,304 f
  unsigned short* st   = (unsigned short*)(ws + 4194304);             // spans 8,388,608 f
  unsigned short* weff = (unsigned short*)(ws + 4194304 + 8388608);   // spans 8,388,608 f
  unsigned short* xbT  = (unsigned short*)(ws + 4194304 + 16777216);  // spans 16,777,216 f
  unsigned short* vwT  = (unsigned short*)(ws + 4194304 + 33554432);  // spans 131,072 f
  unsigned short* qkTh = (unsigned short*)(ws + 4194304 + 33554432 + 131072);  // 65,536 f
  unsigned short* qkTl = qkTh + 131072;                               // 65,536 f
  float* rsum    = ws + 4194304 + 33554432 + 131072 + 131072;         // 32,768 f
  float* attbias = rsum + 32768;                                      // 32,768 f

  // T1: xbT[b][n][c] = bf16(x[b][c][n])
  transpose_conv<<<dim3(16, 8, 64), 256, 0, stream>>>(x, xbT, 512, 1024, 524288L, 524288L);
  // T2: vwT[c][i] = bf16(vw[i][c])
  transpose_conv<<<dim3(8, 8, 1), 256, 0, stream>>>(vw, vwT, 512, 512, 0L, 0L);
  // T3: split-transposed [Qm|Km] -> qkTh/qkTl [128][1024]
  qkm_split<<<dim3(16, 2), 256, 0, stream>>>(Qm, Km, qkTh, qkTl);
  // K1: qk = x @ [Qm|Km], split-bf16 MFMA
  k1_mfma<<<512, 256, 0, stream>>>(x, qkTh, qkTl, qk);
  // K2a: st[b,j,i] = exp(sigmoid(q_i . k_j)), split-bf16 MFMA
  k2a_mfma<<<dim3(4, 4, 64), 256, 0, stream>>>(qk, st);
  // K2b: rsum, attbias
  k2b_rsum<<<8192, 256, 0, stream>>>(st, vb, rsum, attbias);
  // K3: weff = diag(rsum) . st . Vw   (A=vwT, B=st)
  mfma_nt<0><<<dim3(4, 4, 64), 256, 0, stream>>>(vwT, st, rsum, weff, nullptr);
  // K4: out = weff . xf + attbias     (A=xbT, B=weff)
  mfma_nt<1><<<dim3(4, 8, 64), 256, 0, stream>>>(xbT, weff, attbias, nullptr, out);
}